// Round 1
// baseline (5502.052 us; speedup 1.0000x reference)
//
#include <hip/hip_runtime.h>

typedef unsigned short u16;
typedef unsigned int u32;
typedef __attribute__((ext_vector_type(8))) short short8;
typedef __attribute__((ext_vector_type(4))) float float4v;

#define B_SZ 4096
#define T_SZ 32
#define XD 256
#define HD 256
#define ZD 256
#define GD 128
#define YD 2

#define BM 32
#define KP1 776   // a_ga row stride (bf16 elems): 768 + 8 pad
#define KP3 520   // a3 row stride: 512 + 8 pad

// bf16 weight fragment buffer layout in d_ws (elem offsets)
#define W1_OFF 0              // [r|u]  N=512 (NT=32), KT=24
#define W2_OFF 393216         // Wh     N=256 (NT=16), KT=24
#define W3_OFF 589824         // zp|zq  N=512 (NT=32), KT=17
#define W4_OFF 868352         // pm|ps|qm|qs N=1024 (NT=64), KT=8
#define WG_OFF 1130496        // Wg     N=128 (NT=8),  KT=24
#define WTOT   1228800

#define YTOT  (B_SZ*T_SZ*YD)        // 262144
#define KLTOT (B_SZ*T_SZ)           // 131072

__device__ __forceinline__ u16 f2bf(float f) {
    u32 u = __float_as_uint(f);
    u32 r = (u + 0x7fffu + ((u >> 16) & 1u)) >> 16;
    return (u16)r;
}
__device__ __forceinline__ float bf2f(u16 h) {
    return __uint_as_float(((u32)h) << 16);
}
__device__ __forceinline__ float tanh_f(float x) {
    float e = __expf(2.f * x);
    return 1.f - 2.f / (e + 1.f);
}
__device__ __forceinline__ float sigm_f(float x) {
    return 1.f / (1.f + __expf(-x));
}

// ---------------------------------------------------------------------------
// Weight preprocessing: fp32 [K][N] -> bf16 MFMA B-fragment-contiguous layout.
// For (matrix, ntile, kt): 512 elems, addr = base + ((ntile*KT + kt)<<9) + lane*8 + j
// where lane = (n&15) | (((k>>3)&3)<<4), j = k&7.
// ---------------------------------------------------------------------------
__global__ void prep_weights(const float* __restrict__ Wr, const float* __restrict__ Wu,
                             const float* __restrict__ Wh, const float* __restrict__ Wzp,
                             const float* __restrict__ Wzq, const float* __restrict__ Wpm,
                             const float* __restrict__ Wps, const float* __restrict__ Wqm,
                             const float* __restrict__ Wqs, const float* __restrict__ Wg,
                             u16* __restrict__ wts)
{
    int o = blockIdx.x * 256 + threadIdx.x;
    if (o >= WTOT) return;
    int mat, w, KT;
    if (o < W2_OFF)      { mat = 0; w = o;          KT = 24; }
    else if (o < W3_OFF) { mat = 1; w = o - W2_OFF; KT = 24; }
    else if (o < W4_OFF) { mat = 2; w = o - W3_OFF; KT = 17; }
    else if (o < WG_OFF) { mat = 3; w = o - W4_OFF; KT = 8;  }
    else                 { mat = 4; w = o - WG_OFF; KT = 24; }
    int nt  = w / (KT * 512);
    int rem = w - nt * (KT * 512);
    int kt  = rem >> 9;
    int q   = rem & 511;
    int lane = q >> 3, j = q & 7;
    int n = (nt << 4) | (lane & 15);
    int k = (kt << 5) + ((lane >> 4) << 3) + j;
    float v = 0.f;
    switch (mat) {
        case 0: v = (n < 256) ? Wr[k * 256 + n] : Wu[k * 256 + (n - 256)]; break;
        case 1: v = Wh[k * 256 + n]; break;
        case 2: v = (n < 256) ? (k < 512 ? Wzp[k * 256 + n] : 0.f)
                              : (k < 514 ? Wzq[k * 256 + (n - 256)] : 0.f); break;
        case 3: { int sel = n >> 8; int nn = n & 255;
                  const float* s = (sel == 0) ? Wpm : (sel == 1) ? Wps : (sel == 2) ? Wqm : Wqs;
                  v = s[k * 256 + nn]; } break;
        default: v = Wg[k * 128 + n]; break;
    }
    wts[o] = f2bf(v);
}

// ---------------------------------------------------------------------------
// Persistent VRNN kernel: one block owns BM=32 batch rows for all 32 steps.
// 512 threads = 8 waves. All GEMMs via v_mfma_f32_16x16x32_bf16.
// A-frag: row = lane&15, k = (lane>>4)*8 + j.   B-frag: col = lane&15, same k.
// C-frag: col = lane&15, row = (lane>>4)*4 + reg.
// ---------------------------------------------------------------------------
__global__ __launch_bounds__(512, 2) void vrnn_all(
    const float* __restrict__ x,   const float* __restrict__ y_ph,
    const int*   __restrict__ Tph, const float* __restrict__ h0,
    const float* __restrict__ z0,  const float* __restrict__ eps,
    const float* __restrict__ br,  const float* __restrict__ bu,
    const float* __restrict__ bh,  const float* __restrict__ bzp,
    const float* __restrict__ bpm, const float* __restrict__ bps,
    const float* __restrict__ bzq, const float* __restrict__ bqm,
    const float* __restrict__ bqs, const float* __restrict__ bg,
    const float* __restrict__ by,  const float* __restrict__ Wy,
    const u16*   __restrict__ wts, float* __restrict__ out)
{
    __shared__ __align__(16) u16   a_ga[BM * KP1];   // [x | h-ish | z-ish] bf16
    __shared__ __align__(16) u16   a3s[BM * KP3];    // [hzp | hzq] bf16
    __shared__ __align__(16) float h32[BM * HD];     // fp32 recurrent h
    __shared__ __align__(16) u16   u_bf[BM * HD];
    __shared__ __align__(16) float g_sm[BM * GD];
    __shared__ float kl_acc[BM];
    __shared__ float wy_sm[GD * 2 + 2];

    const int tid  = threadIdx.x;
    const int wv   = tid >> 6;
    const int lane = tid & 63;
    const int quad = lane >> 4;
    const int l15  = lane & 15;
    const int b0   = blockIdx.x * BM;
    const int akof = quad * 8;   // A/B k sub-offset

    for (int i = tid; i < GD * 2; i += 512) wy_sm[i] = Wy[i];
    if (tid < 2) wy_sm[GD * 2 + tid] = by[tid];

    // init h, z state
    for (int i = tid; i < BM * HD; i += 512) {
        int r = i >> 8, c = i & 255;
        float h = h0[(b0 + r) * HD + c];
        h32[i] = h;
        a_ga[r * KP1 + 256 + c] = f2bf(h);
        a_ga[r * KP1 + 512 + c] = f2bf(z0[(b0 + r) * ZD + c]);
    }
    __syncthreads();

    const float4v zero4 = {0.f, 0.f, 0.f, 0.f};

    for (int t = 0; t < T_SZ; ++t) {
        // refresh x_t section
        for (int i = tid; i < BM * XD; i += 512) {
            int r = i >> 8, c = i & 255;
            a_ga[r * KP1 + c] = f2bf(x[((size_t)(b0 + r) * T_SZ + t) * XD + c]);
        }
        __syncthreads();

        // ================= stage 1: [r|u] = sigmoid(ga @ [Wr|Wu]) ==========
        {
            float4v acc[2][4];
            for (int m = 0; m < 2; ++m)
                for (int n = 0; n < 4; ++n) acc[m][n] = zero4;
            const int n0 = wv * 64;
            for (int kt = 0; kt < 24; ++kt) {
                short8 aF0 = *(const short8*)&a_ga[l15 * KP1 + kt * 32 + akof];
                short8 aF1 = *(const short8*)&a_ga[(16 + l15) * KP1 + kt * 32 + akof];
#pragma unroll
                for (int nt = 0; nt < 4; ++nt) {
                    int ntile = wv * 4 + nt;
                    short8 bF = *(const short8*)&wts[W1_OFF + (((ntile * 24) + kt) << 9) + lane * 8];
                    acc[0][nt] = __builtin_amdgcn_mfma_f32_16x16x32_bf16(aF0, bF, acc[0][nt], 0, 0, 0);
                    acc[1][nt] = __builtin_amdgcn_mfma_f32_16x16x32_bf16(aF1, bF, acc[1][nt], 0, 0, 0);
                }
            }
            __syncthreads();   // all waves done reading a_ga before mid overwrite
#pragma unroll
            for (int m = 0; m < 2; ++m)
#pragma unroll
                for (int nt = 0; nt < 4; ++nt)
#pragma unroll
                    for (int i = 0; i < 4; ++i) {
                        int row = m * 16 + quad * 4 + i;
                        int col = n0 + nt * 16 + l15;
                        float v = acc[m][nt][i];
                        if (col < 256) {
                            float rr = sigm_f(v + br[col]);
                            a_ga[row * KP1 + 256 + col] = f2bf(rr * h32[row * HD + col]);
                        } else {
                            int c2 = col - 256;
                            float uu = sigm_f(v + bu[c2]);
                            u_bf[row * HD + c2] = f2bf(uu);
                        }
                    }
            __syncthreads();
        }

        // ================= stage 2: h_tilde, h update ======================
        {
            float4v acc[2][2];
            for (int m = 0; m < 2; ++m)
                for (int n = 0; n < 2; ++n) acc[m][n] = zero4;
            const int n0 = wv * 32;
            for (int kt = 0; kt < 24; ++kt) {
                short8 aF0 = *(const short8*)&a_ga[l15 * KP1 + kt * 32 + akof];
                short8 aF1 = *(const short8*)&a_ga[(16 + l15) * KP1 + kt * 32 + akof];
#pragma unroll
                for (int nt = 0; nt < 2; ++nt) {
                    int ntile = wv * 2 + nt;
                    short8 bF = *(const short8*)&wts[W2_OFF + (((ntile * 24) + kt) << 9) + lane * 8];
                    acc[0][nt] = __builtin_amdgcn_mfma_f32_16x16x32_bf16(aF0, bF, acc[0][nt], 0, 0, 0);
                    acc[1][nt] = __builtin_amdgcn_mfma_f32_16x16x32_bf16(aF1, bF, acc[1][nt], 0, 0, 0);
                }
            }
            __syncthreads();
#pragma unroll
            for (int m = 0; m < 2; ++m)
#pragma unroll
                for (int nt = 0; nt < 2; ++nt)
#pragma unroll
                    for (int i = 0; i < 4; ++i) {
                        int row = m * 16 + quad * 4 + i;
                        int col = n0 + nt * 16 + l15;
                        float ht = tanh_f(acc[m][nt][i] + bh[col]);
                        float uu = bf2f(u_bf[row * HD + col]);
                        float hp = h32[row * HD + col];
                        float h  = (1.f - uu) * hp + uu * ht;
                        h32[row * HD + col] = h;
                        a_ga[row * KP1 + 256 + col] = f2bf(h);
                    }
            // y_t + zero pad into cols [512, 544)
            for (int i = tid; i < BM * 32; i += 512) {
                int r = i >> 5, c = i & 31;
                u16 v = 0;
                if (c < 2) v = f2bf(y_ph[((size_t)(b0 + r) * T_SZ + t) * YD + c]);
                a_ga[r * KP1 + 512 + c] = v;
            }
            __syncthreads();
        }

        // ================= stage 3: hzp|hzq = tanh([x|h|y] @ W3) ===========
        {
            float4v acc[2][4];
            for (int m = 0; m < 2; ++m)
                for (int n = 0; n < 4; ++n) acc[m][n] = zero4;
            const int n0 = wv * 64;
            for (int kt = 0; kt < 17; ++kt) {
                short8 aF0 = *(const short8*)&a_ga[l15 * KP1 + kt * 32 + akof];
                short8 aF1 = *(const short8*)&a_ga[(16 + l15) * KP1 + kt * 32 + akof];
#pragma unroll
                for (int nt = 0; nt < 4; ++nt) {
                    int ntile = wv * 4 + nt;
                    short8 bF = *(const short8*)&wts[W3_OFF + (((ntile * 17) + kt) << 9) + lane * 8];
                    acc[0][nt] = __builtin_amdgcn_mfma_f32_16x16x32_bf16(aF0, bF, acc[0][nt], 0, 0, 0);
                    acc[1][nt] = __builtin_amdgcn_mfma_f32_16x16x32_bf16(aF1, bF, acc[1][nt], 0, 0, 0);
                }
            }
            // a3s not read by stage-3 GEMM: write without pre-sync
#pragma unroll
            for (int m = 0; m < 2; ++m)
#pragma unroll
                for (int nt = 0; nt < 4; ++nt)
#pragma unroll
                    for (int i = 0; i < 4; ++i) {
                        int row = m * 16 + quad * 4 + i;
                        int col = n0 + nt * 16 + l15;
                        float b = (col < 256) ? bzp[col] : bzq[col - 256];
                        a3s[row * KP3 + col] = f2bf(tanh_f(acc[m][nt][i] + b));
                    }
            if (tid < BM) kl_acc[tid] = 0.f;
            __syncthreads();
        }

        // ================= stage 4: mu/s (p,q), z_post, KL =================
        {
            float4v acc[4][2][2];   // [mat][m][nt]
            for (int a = 0; a < 4; ++a)
                for (int m = 0; m < 2; ++m)
                    for (int n = 0; n < 2; ++n) acc[a][m][n] = zero4;
            const int n0 = wv * 32;
            for (int kt = 0; kt < 8; ++kt) {
                short8 aP0 = *(const short8*)&a3s[l15 * KP3 + kt * 32 + akof];
                short8 aP1 = *(const short8*)&a3s[(16 + l15) * KP3 + kt * 32 + akof];
                short8 aQ0 = *(const short8*)&a3s[l15 * KP3 + 256 + kt * 32 + akof];
                short8 aQ1 = *(const short8*)&a3s[(16 + l15) * KP3 + 256 + kt * 32 + akof];
#pragma unroll
                for (int nt = 0; nt < 2; ++nt) {
                    int ntile = wv * 2 + nt;
                    short8 b0f = *(const short8*)&wts[W4_OFF + (((ntile      ) * 8 + kt) << 9) + lane * 8];
                    short8 b1f = *(const short8*)&wts[W4_OFF + (((ntile + 16) * 8 + kt) << 9) + lane * 8];
                    short8 b2f = *(const short8*)&wts[W4_OFF + (((ntile + 32) * 8 + kt) << 9) + lane * 8];
                    short8 b3f = *(const short8*)&wts[W4_OFF + (((ntile + 48) * 8 + kt) << 9) + lane * 8];
                    acc[0][0][nt] = __builtin_amdgcn_mfma_f32_16x16x32_bf16(aP0, b0f, acc[0][0][nt], 0, 0, 0);
                    acc[0][1][nt] = __builtin_amdgcn_mfma_f32_16x16x32_bf16(aP1, b0f, acc[0][1][nt], 0, 0, 0);
                    acc[1][0][nt] = __builtin_amdgcn_mfma_f32_16x16x32_bf16(aP0, b1f, acc[1][0][nt], 0, 0, 0);
                    acc[1][1][nt] = __builtin_amdgcn_mfma_f32_16x16x32_bf16(aP1, b1f, acc[1][1][nt], 0, 0, 0);
                    acc[2][0][nt] = __builtin_amdgcn_mfma_f32_16x16x32_bf16(aQ0, b2f, acc[2][0][nt], 0, 0, 0);
                    acc[2][1][nt] = __builtin_amdgcn_mfma_f32_16x16x32_bf16(aQ1, b2f, acc[2][1][nt], 0, 0, 0);
                    acc[3][0][nt] = __builtin_amdgcn_mfma_f32_16x16x32_bf16(aQ0, b3f, acc[3][0][nt], 0, 0, 0);
                    acc[3][1][nt] = __builtin_amdgcn_mfma_f32_16x16x32_bf16(aQ1, b3f, acc[3][1][nt], 0, 0, 0);
                }
            }
            float klsum[2][4];
            for (int m = 0; m < 2; ++m)
                for (int i = 0; i < 4; ++i) klsum[m][i] = 0.f;
#pragma unroll
            for (int m = 0; m < 2; ++m)
#pragma unroll
                for (int nt = 0; nt < 2; ++nt)
#pragma unroll
                    for (int i = 0; i < 4; ++i) {
                        int row = m * 16 + quad * 4 + i;
                        int zc  = n0 + nt * 16 + l15;
                        float mu_p = acc[0][m][nt][i] + bpm[zc];
                        float s_p  = acc[1][m][nt][i] + bps[zc];
                        float mu_q = acc[2][m][nt][i] + bqm[zc];
                        float s_q  = acc[3][m][nt][i] + bqs[zc];
                        float e = eps[((size_t)t * B_SZ + (b0 + row)) * ZD + zc];
                        float zpost = mu_q + __expf(0.5f * s_q) * e;
                        float dmu = mu_q - mu_p;
                        klsum[m][i] += 0.5f * (s_p - s_q)
                                     + (__expf(s_q) + dmu * dmu) * 0.5f * __expf(-s_p) - 0.5f;
                        a_ga[row * KP1 + 512 + zc] = f2bf(zpost);
                    }
#pragma unroll
            for (int m = 0; m < 2; ++m)
#pragma unroll
                for (int i = 0; i < 4; ++i) {
                    float v = klsum[m][i];
                    v += __shfl_xor(v, 1); v += __shfl_xor(v, 2);
                    v += __shfl_xor(v, 4); v += __shfl_xor(v, 8);
                    if (l15 == 0) atomicAdd(&kl_acc[m * 16 + quad * 4 + i], v);
                }
            __syncthreads();
            if (tid < BM)
                out[YTOT + (size_t)(b0 + tid) * T_SZ + t] = kl_acc[tid];
        }

        // ================= stage 5: g, y=softmax(g@Wy), g_T ================
        {
            float4v acc5[2];
            acc5[0] = zero4; acc5[1] = zero4;
            for (int kt = 0; kt < 24; ++kt) {
                short8 aF0 = *(const short8*)&a_ga[l15 * KP1 + kt * 32 + akof];
                short8 aF1 = *(const short8*)&a_ga[(16 + l15) * KP1 + kt * 32 + akof];
                short8 bF = *(const short8*)&wts[WG_OFF + ((wv * 24 + kt) << 9) + lane * 8];
                acc5[0] = __builtin_amdgcn_mfma_f32_16x16x32_bf16(aF0, bF, acc5[0], 0, 0, 0);
                acc5[1] = __builtin_amdgcn_mfma_f32_16x16x32_bf16(aF1, bF, acc5[1], 0, 0, 0);
            }
#pragma unroll
            for (int m = 0; m < 2; ++m)
#pragma unroll
                for (int i = 0; i < 4; ++i) {
                    int row = m * 16 + quad * 4 + i;
                    int col = wv * 16 + l15;
                    g_sm[row * GD + col] = tanh_f(acc5[m][i] + bg[col]);
                }
            __syncthreads();
            // y head: 4 threads per row
            if (tid < 128) {
                int r = tid >> 2, q = tid & 3;
                float p0 = 0.f, p1 = 0.f;
                for (int c = q * 32; c < q * 32 + 32; ++c) {
                    float gv = g_sm[r * GD + c];
                    p0 += gv * wy_sm[c * 2 + 0];
                    p1 += gv * wy_sm[c * 2 + 1];
                }
                p0 += __shfl_xor(p0, 1); p0 += __shfl_xor(p0, 2);
                p1 += __shfl_xor(p1, 1); p1 += __shfl_xor(p1, 2);
                if (q == 0) {
                    float l0 = p0 + wy_sm[256], l1 = p1 + wy_sm[257];
                    float mx = fmaxf(l0, l1);
                    float e0 = __expf(l0 - mx), e1 = __expf(l1 - mx);
                    float inv = 1.f / (e0 + e1);
                    size_t yoff = ((size_t)(b0 + r) * T_SZ + t) * YD;
                    out[yoff]     = e0 * inv;
                    out[yoff + 1] = e1 * inv;
                }
            }
            // g_T gather (exactly one t per row matches)
            for (int i = tid; i < BM * GD; i += 512) {
                int r = i >> 7, c = i & 127;
                if (Tph[b0 + r] - 1 == t)
                    out[YTOT + KLTOT + (size_t)(b0 + r) * GD + c] = g_sm[r * GD + c];
            }
            __syncthreads();
        }
    }
}

extern "C" void kernel_launch(void* const* d_in, const int* in_sizes, int n_in,
                              void* d_out, int out_size, void* d_ws, size_t ws_size,
                              hipStream_t stream)
{
    const float* x   = (const float*)d_in[0];
    const float* yph = (const float*)d_in[1];
    const int*   Tph = (const int*)  d_in[2];
    const float* h0  = (const float*)d_in[3];
    const float* z0  = (const float*)d_in[4];
    const float* eps = (const float*)d_in[5];
    const float* Wr  = (const float*)d_in[6];
    const float* br  = (const float*)d_in[7];
    const float* Wu  = (const float*)d_in[8];
    const float* bu  = (const float*)d_in[9];
    const float* Wh  = (const float*)d_in[10];
    const float* bh  = (const float*)d_in[11];
    const float* Wzp = (const float*)d_in[12];
    const float* bzp = (const float*)d_in[13];
    const float* Wpm = (const float*)d_in[14];
    const float* bpm = (const float*)d_in[15];
    const float* Wps = (const float*)d_in[16];
    const float* bps = (const float*)d_in[17];
    const float* Wzq = (const float*)d_in[18];
    const float* bzq = (const float*)d_in[19];
    const float* Wqm = (const float*)d_in[20];
    const float* bqm = (const float*)d_in[21];
    const float* Wqs = (const float*)d_in[22];
    const float* bqs = (const float*)d_in[23];
    const float* Wg  = (const float*)d_in[24];
    const float* bg  = (const float*)d_in[25];
    const float* Wy  = (const float*)d_in[26];
    const float* by  = (const float*)d_in[27];
    u16*   wts = (u16*)d_ws;
    float* out = (float*)d_out;

    hipLaunchKernelGGL(prep_weights, dim3((WTOT + 255) / 256), dim3(256), 0, stream,
                       Wr, Wu, Wh, Wzp, Wzq, Wpm, Wps, Wqm, Wqs, Wg, wts);
    hipLaunchKernelGGL(vrnn_all, dim3(B_SZ / BM), dim3(512), 0, stream,
                       x, yph, Tph, h0, z0, eps, br, bu, bh, bzp, bpm, bps,
                       bzq, bqm, bqs, bg, by, Wy, wts, out);
}

// Round 2
// 4635.056 us; speedup vs baseline: 1.1871x; 1.1871x over previous
//
#include <hip/hip_runtime.h>

typedef unsigned short u16;
typedef unsigned int u32;
typedef __attribute__((ext_vector_type(8))) short short8;
typedef __attribute__((ext_vector_type(4))) float float4v;

#define B_SZ 4096
#define T_SZ 32
#define XD 256
#define HD 256
#define ZD 256
#define GD 128
#define YD 2

#define BM 32          // batch rows per block
#define NW 16          // waves per block (1024 threads)

// bf16 weight fragment buffer layout in d_ws (elem offsets) — frag-contiguous:
// addr = base + ((ntile*KT + kt)<<9) + lane*8 + j ; lane=(n&15)|(((k>>3)&3)<<4), j=k&7
#define W1_OFF 0              // [Wr|Wu]  N=512 (32 ntiles), KT=24
#define W2_OFF 393216         // Wh       N=256 (16 ntiles), KT=24
#define W3_OFF 589824         // [Wzp|Wzq] N=512 (32 ntiles), KT=17 (K=544: x,h,y+pad)
#define W4_OFF 868352         // [Wpm|Wps|Wqm|Wqs] N=1024 (64 ntiles), KT=8
#define WG_OFF 1130496        // Wg       N=128 (8 ntiles),  KT=24
#define WTOT   1228800

#define YTOT  (B_SZ*T_SZ*YD)        // 262144
#define KLTOT (B_SZ*T_SZ)           // 131072

#define HST 260    // h32 row stride (floats)
#define UST 264    // u_bf row stride (bf16)

__device__ __forceinline__ u16 f2bf(float f) {
    u32 u = __float_as_uint(f);
    u32 r = (u + 0x7fffu + ((u >> 16) & 1u)) >> 16;
    return (u16)r;
}
__device__ __forceinline__ float bf2f(u16 h) {
    return __uint_as_float(((u32)h) << 16);
}
__device__ __forceinline__ float tanh_f(float x) {
    float e = __expf(2.f * x);
    return 1.f - 2.f / (e + 1.f);
}
__device__ __forceinline__ float sigm_f(float x) {
    return 1.f / (1.f + __expf(-x));
}

// a_ga: 48 tiles (mt*24+kt) of 512 elems, frag-contiguous
__device__ __forceinline__ int aga_off(int r, int k) {
    return (((r >> 4) * 24 + (k >> 5)) << 9) + ((((k >> 3) & 3) * 16 + (r & 15)) << 3) + (k & 7);
}
// a3s: 32 tiles ((pq*2+mt)*8+kt) of 512 elems
__device__ __forceinline__ int a3s_off(int r, int k, int pq) {
    return (((pq * 2 + (r >> 4)) * 8 + (k >> 5)) << 9) + ((((k >> 3) & 3) * 16 + (r & 15)) << 3) + (k & 7);
}

#define MFMA(a, b, c) __builtin_amdgcn_mfma_f32_16x16x32_bf16(a, b, c, 0, 0, 0)

// ---------------------------------------------------------------------------
__global__ void prep_weights(const float* __restrict__ Wr, const float* __restrict__ Wu,
                             const float* __restrict__ Wh, const float* __restrict__ Wzp,
                             const float* __restrict__ Wzq, const float* __restrict__ Wpm,
                             const float* __restrict__ Wps, const float* __restrict__ Wqm,
                             const float* __restrict__ Wqs, const float* __restrict__ Wg,
                             u16* __restrict__ wts)
{
    int o = blockIdx.x * 256 + threadIdx.x;
    if (o >= WTOT) return;
    int mat, w, KT;
    if (o < W2_OFF)      { mat = 0; w = o;          KT = 24; }
    else if (o < W3_OFF) { mat = 1; w = o - W2_OFF; KT = 24; }
    else if (o < W4_OFF) { mat = 2; w = o - W3_OFF; KT = 17; }
    else if (o < WG_OFF) { mat = 3; w = o - W4_OFF; KT = 8;  }
    else                 { mat = 4; w = o - WG_OFF; KT = 24; }
    int nt  = w / (KT * 512);
    int rem = w - nt * (KT * 512);
    int kt  = rem >> 9;
    int q   = rem & 511;
    int lane = q >> 3, j = q & 7;
    int n = (nt << 4) | (lane & 15);
    int k = (kt << 5) + ((lane >> 4) << 3) + j;
    float v = 0.f;
    switch (mat) {
        case 0: v = (n < 256) ? Wr[k * 256 + n] : Wu[k * 256 + (n - 256)]; break;
        case 1: v = Wh[k * 256 + n]; break;
        case 2: v = (n < 256) ? (k < 512 ? Wzp[k * 256 + n] : 0.f)
                              : (k < 514 ? Wzq[k * 256 + (n - 256)] : 0.f); break;
        case 3: { int sel = n >> 8; int nn = n & 255;
                  const float* s = (sel == 0) ? Wpm : (sel == 1) ? Wps : (sel == 2) ? Wqm : Wqs;
                  v = s[k * 256 + nn]; } break;
        default: v = Wg[k * 128 + n]; break;
    }
    wts[o] = f2bf(v);
}

// ---------------------------------------------------------------------------
__global__ __launch_bounds__(1024, 4) void vrnn_all(
    const float* __restrict__ x,   const float* __restrict__ y_ph,
    const int*   __restrict__ Tph, const float* __restrict__ h0,
    const float* __restrict__ z0,  const float* __restrict__ eps,
    const float* __restrict__ br,  const float* __restrict__ bu,
    const float* __restrict__ bh,  const float* __restrict__ bzp,
    const float* __restrict__ bpm, const float* __restrict__ bps,
    const float* __restrict__ bzq, const float* __restrict__ bqm,
    const float* __restrict__ bqs, const float* __restrict__ bg,
    const float* __restrict__ by,  const float* __restrict__ Wy,
    const u16*   __restrict__ wts, float* __restrict__ out)
{
    __shared__ __align__(16) u16   a_ga[48 * 512];   // 49.2 KB  [x|h|z] frag tiles
    __shared__ __align__(16) u16   a3s[32 * 512];    // 32.8 KB  [hzp|hzq] frag tiles
    __shared__ __align__(16) float h32[BM * HST];    // 33.3 KB  fp32 recurrent h
    __shared__ __align__(16) u16   u_bf[BM * UST];   // 16.9 KB
    __shared__ float part[8 * BM * 2];               // 2 KB  y-head partials
    __shared__ float kl_acc[BM];
    __shared__ int   tph_s[BM];

    const int tid  = threadIdx.x;
    const int wv   = tid >> 6;
    const int lane = tid & 63;
    const int quad = lane >> 4;
    const int l15  = lane & 15;
    const int b0   = blockIdx.x * BM;

    // --- per-lane register-resident biases / Wy ---
    const int c10 = wv * 32 + l15;          // stage1 cols (nt=0), +16 for nt=1
    const float bs1_0 = (c10 < 256) ? br[c10] : bu[c10 - 256];
    const float bs1_1 = (c10 + 16 < 256) ? br[c10 + 16] : bu[c10 + 16 - 256];
    const int c2  = wv * 16 + l15;          // stage2 col
    const float bh_r = bh[c2];
    const float bz0 = (c10 < 256) ? bzp[c10] : bzq[c10 - 256];
    const float bz1 = (c10 + 16 < 256) ? bzp[c10 + 16] : bzq[c10 + 16 - 256];
    const int zc  = wv * 16 + l15;          // stage4 col
    const float b4pm = bpm[zc], b4ps = bps[zc], b4qm = bqm[zc], b4qs = bqs[zc];
    const int c5  = (wv >> 1) * 16 + l15;   // stage5 col
    const int mt5 = wv & 1;
    const float bg_r = bg[c5];
    const float wy0 = Wy[c5 * 2], wy1 = Wy[c5 * 2 + 1];
    const float by0 = by[0], by1 = by[1];

    if (tid < BM) tph_s[tid] = Tph[b0 + tid];

    // --- init h, z state ---
    {
        int r = tid >> 5, cc = (tid & 31) * 8;
        const float* hp = &h0[(b0 + r) * HD + cc];
        const float* zp = &z0[(b0 + r) * ZD + cc];
        short8 hv, zv;
#pragma unroll
        for (int j = 0; j < 8; ++j) {
            float hh = hp[j];
            h32[r * HST + cc + j] = hh;
            hv[j] = (short)f2bf(hh);
            zv[j] = (short)f2bf(zp[j]);
        }
        *(short8*)&a_ga[aga_off(r, 256 + cc)] = hv;
        *(short8*)&a_ga[aga_off(r, 512 + cc)] = zv;
    }
    __syncthreads();

    const float4v zero4 = {0.f, 0.f, 0.f, 0.f};

    for (int t = 0; t < T_SZ; ++t) {
        // --- stage x_t into a_ga cols [0,256) ---
        {
            int r = tid >> 5, cc = (tid & 31) * 8;
            const float* xp = &x[((size_t)(b0 + r) * T_SZ + t) * XD + cc];
            short8 xv;
#pragma unroll
            for (int j = 0; j < 8; ++j) xv[j] = (short)f2bf(xp[j]);
            *(short8*)&a_ga[aga_off(r, cc)] = xv;
        }
        __syncthreads();   // bar1

        // ============ stage 1: [r|u] = sigmoid([x,h,z] @ W1) ============
        {
            const u16* pB0 = wts + W1_OFF + (((wv * 2    ) * 24) << 9) + lane * 8;
            const u16* pB1 = wts + W1_OFF + (((wv * 2 + 1) * 24) << 9) + lane * 8;
            float4v a00 = zero4, a01 = zero4, a10 = zero4, a11 = zero4;
            short8 b0c = *(const short8*)pB0;
            short8 b1c = *(const short8*)pB1;
            for (int kt = 0; kt < 24; ++kt) {
                int kn = (kt < 23) ? kt + 1 : 23;
                short8 b0n = *(const short8*)(pB0 + (kn << 9));
                short8 b1n = *(const short8*)(pB1 + (kn << 9));
                short8 aF0 = *(const short8*)&a_ga[(kt << 9) + lane * 8];
                short8 aF1 = *(const short8*)&a_ga[((24 + kt) << 9) + lane * 8];
                a00 = MFMA(aF0, b0c, a00); a01 = MFMA(aF0, b1c, a01);
                a10 = MFMA(aF1, b0c, a10); a11 = MFMA(aF1, b1c, a11);
                b0c = b0n; b1c = b1n;
            }
            __syncthreads();   // bar2: all a_ga reads done before rh overwrite
#pragma unroll
            for (int mt = 0; mt < 2; ++mt) {
                const float4v* am = (mt == 0) ? &a00 : &a10;
                const float4v* an = (mt == 0) ? &a01 : &a11;
#pragma unroll
                for (int i = 0; i < 4; ++i) {
                    int row = mt * 16 + quad * 4 + i;
                    // nt = 0
                    {
                        int c = c10;
                        float v = (*am)[i];
                        if (c < 256) {
                            float rr = sigm_f(v + bs1_0);
                            a_ga[aga_off(row, 256 + c)] = f2bf(rr * h32[row * HST + c]);
                        } else {
                            u_bf[row * UST + (c - 256)] = f2bf(sigm_f(v + bs1_0));
                        }
                    }
                    // nt = 1
                    {
                        int c = c10 + 16;
                        float v = (*an)[i];
                        if (c < 256) {
                            float rr = sigm_f(v + bs1_1);
                            a_ga[aga_off(row, 256 + c)] = f2bf(rr * h32[row * HST + c]);
                        } else {
                            u_bf[row * UST + (c - 256)] = f2bf(sigm_f(v + bs1_1));
                        }
                    }
                }
            }
            __syncthreads();   // bar3
        }

        // ============ stage 2: h_tilde = tanh([x,rh,z] @ Wh); h update ============
        {
            const u16* pB = wts + W2_OFF + ((wv * 24) << 9) + lane * 8;
            float4v a0 = zero4, a1 = zero4;
            short8 bc = *(const short8*)pB;
            for (int kt = 0; kt < 24; ++kt) {
                int kn = (kt < 23) ? kt + 1 : 23;
                short8 bn = *(const short8*)(pB + (kn << 9));
                short8 aF0 = *(const short8*)&a_ga[(kt << 9) + lane * 8];
                short8 aF1 = *(const short8*)&a_ga[((24 + kt) << 9) + lane * 8];
                a0 = MFMA(aF0, bc, a0);
                a1 = MFMA(aF1, bc, a1);
                bc = bn;
            }
            __syncthreads();   // bar4: a_ga reads done before h / y writes
#pragma unroll
            for (int mt = 0; mt < 2; ++mt) {
                const float4v* am = (mt == 0) ? &a0 : &a1;
#pragma unroll
                for (int i = 0; i < 4; ++i) {
                    int row = mt * 16 + quad * 4 + i;
                    float ht = tanh_f((*am)[i] + bh_r);
                    float uu = bf2f(u_bf[row * UST + c2]);
                    float hp = h32[row * HST + c2];
                    float h  = (1.f - uu) * hp + uu * ht;
                    h32[row * HST + c2] = h;
                    a_ga[aga_off(row, 256 + c2)] = f2bf(h);
                }
            }
            // y_t + zeros into cols [512,544) (tile kt=16)
            if (tid < 128) {
                int r = tid >> 2, grp = tid & 3;
                short8 v = {0, 0, 0, 0, 0, 0, 0, 0};
                if (grp == 0) {
                    const float* yp = &y_ph[((size_t)(b0 + r) * T_SZ + t) * YD];
                    v[0] = (short)f2bf(yp[0]);
                    v[1] = (short)f2bf(yp[1]);
                }
                *(short8*)&a_ga[aga_off(r, 512 + grp * 8)] = v;
            }
            __syncthreads();   // bar5
        }

        // ============ stage 3: [hzp|hzq] = tanh([x,h,y] @ W3) ============
        {
            const u16* pB0 = wts + W3_OFF + (((wv * 2    ) * 17) << 9) + lane * 8;
            const u16* pB1 = wts + W3_OFF + (((wv * 2 + 1) * 17) << 9) + lane * 8;
            float4v a00 = zero4, a01 = zero4, a10 = zero4, a11 = zero4;
            short8 b0c = *(const short8*)pB0;
            short8 b1c = *(const short8*)pB1;
            for (int kt = 0; kt < 17; ++kt) {
                int kn = (kt < 16) ? kt + 1 : 16;
                short8 b0n = *(const short8*)(pB0 + (kn << 9));
                short8 b1n = *(const short8*)(pB1 + (kn << 9));
                short8 aF0 = *(const short8*)&a_ga[(kt << 9) + lane * 8];
                short8 aF1 = *(const short8*)&a_ga[((24 + kt) << 9) + lane * 8];
                a00 = MFMA(aF0, b0c, a00); a01 = MFMA(aF0, b1c, a01);
                a10 = MFMA(aF1, b0c, a10); a11 = MFMA(aF1, b1c, a11);
                b0c = b0n; b1c = b1n;
            }
            // a3s write needs no pre-barrier (last read ≥2 barriers ago)
#pragma unroll
            for (int mt = 0; mt < 2; ++mt) {
                const float4v* am = (mt == 0) ? &a00 : &a10;
                const float4v* an = (mt == 0) ? &a01 : &a11;
#pragma unroll
                for (int i = 0; i < 4; ++i) {
                    int row = mt * 16 + quad * 4 + i;
                    {
                        int c = c10;
                        float hz = tanh_f((*am)[i] + bz0);
                        a3s[a3s_off(row, c & 255, c >> 8)] = f2bf(hz);
                    }
                    {
                        int c = c10 + 16;
                        float hz = tanh_f((*an)[i] + bz1);
                        a3s[a3s_off(row, c & 255, c >> 8)] = f2bf(hz);
                    }
                }
            }
            if (tid < BM) kl_acc[tid] = 0.f;
            __syncthreads();   // bar6
        }

        // ============ stage 4: mu/s heads, z_post, KL ============
        {
            const u16* pB0 = wts + W4_OFF + (((0 * 16 + wv) * 8) << 9) + lane * 8;
            const u16* pB1 = wts + W4_OFF + (((1 * 16 + wv) * 8) << 9) + lane * 8;
            const u16* pB2 = wts + W4_OFF + (((2 * 16 + wv) * 8) << 9) + lane * 8;
            const u16* pB3 = wts + W4_OFF + (((3 * 16 + wv) * 8) << 9) + lane * 8;
            float4v ac[4][2];
#pragma unroll
            for (int m = 0; m < 4; ++m) { ac[m][0] = zero4; ac[m][1] = zero4; }
            for (int kt = 0; kt < 8; ++kt) {
                short8 bm0 = *(const short8*)(pB0 + (kt << 9));
                short8 bm1 = *(const short8*)(pB1 + (kt << 9));
                short8 bm2 = *(const short8*)(pB2 + (kt << 9));
                short8 bm3 = *(const short8*)(pB3 + (kt << 9));
                short8 aP0 = *(const short8*)&a3s[((0 + kt) << 9) + lane * 8];          // P, mt0
                short8 aP1 = *(const short8*)&a3s[((8 + kt) << 9) + lane * 8];          // P, mt1
                short8 aQ0 = *(const short8*)&a3s[((16 + kt) << 9) + lane * 8];         // Q, mt0
                short8 aQ1 = *(const short8*)&a3s[((24 + kt) << 9) + lane * 8];         // Q, mt1
                ac[0][0] = MFMA(aP0, bm0, ac[0][0]); ac[0][1] = MFMA(aP1, bm0, ac[0][1]);
                ac[1][0] = MFMA(aP0, bm1, ac[1][0]); ac[1][1] = MFMA(aP1, bm1, ac[1][1]);
                ac[2][0] = MFMA(aQ0, bm2, ac[2][0]); ac[2][1] = MFMA(aQ1, bm2, ac[2][1]);
                ac[3][0] = MFMA(aQ0, bm3, ac[3][0]); ac[3][1] = MFMA(aQ1, bm3, ac[3][1]);
            }
            float kls[2][4];
#pragma unroll
            for (int mt = 0; mt < 2; ++mt)
#pragma unroll
                for (int i = 0; i < 4; ++i) {
                    int row = mt * 16 + quad * 4 + i;
                    float mu_p = ac[0][mt][i] + b4pm;
                    float s_p  = ac[1][mt][i] + b4ps;
                    float mu_q = ac[2][mt][i] + b4qm;
                    float s_q  = ac[3][mt][i] + b4qs;
                    float e = eps[((size_t)t * B_SZ + (b0 + row)) * ZD + zc];
                    float zpost = mu_q + __expf(0.5f * s_q) * e;
                    float dmu = mu_q - mu_p;
                    kls[mt][i] = 0.5f * (s_p - s_q)
                               + (__expf(s_q) + dmu * dmu) * 0.5f * __expf(-s_p) - 0.5f;
                    a_ga[aga_off(row, 512 + zc)] = f2bf(zpost);
                }
#pragma unroll
            for (int mt = 0; mt < 2; ++mt)
#pragma unroll
                for (int i = 0; i < 4; ++i) {
                    float v = kls[mt][i];
                    v += __shfl_xor(v, 1); v += __shfl_xor(v, 2);
                    v += __shfl_xor(v, 4); v += __shfl_xor(v, 8);
                    if (l15 == 0) atomicAdd(&kl_acc[mt * 16 + quad * 4 + i], v);
                }
            __syncthreads();   // bar7
            if (tid < BM)
                out[YTOT + (size_t)(b0 + tid) * T_SZ + t] = kl_acc[tid];
        }

        // ============ stage 5: g = tanh([x,h,z] @ Wg); y, g_T ============
        {
            const u16* pB = wts + WG_OFF + (((wv >> 1) * 24) << 9) + lane * 8;
            float4v a5 = zero4;
            short8 bc = *(const short8*)pB;
            const int abase = mt5 * 24;
            for (int kt = 0; kt < 24; ++kt) {
                int kn = (kt < 23) ? kt + 1 : 23;
                short8 bn = *(const short8*)(pB + (kn << 9));
                short8 aF = *(const short8*)&a_ga[((abase + kt) << 9) + lane * 8];
                a5 = MFMA(aF, bc, a5);
                bc = bn;
            }
            float g[4];
#pragma unroll
            for (int i = 0; i < 4; ++i) {
                int row = mt5 * 16 + quad * 4 + i;
                g[i] = tanh_f(a5[i] + bg_r);
                if (tph_s[row] - 1 == t)
                    out[YTOT + KLTOT + (size_t)(b0 + row) * GD + c5] = g[i];
            }
#pragma unroll
            for (int i = 0; i < 4; ++i) {
                float p0 = g[i] * wy0, p1 = g[i] * wy1;
                p0 += __shfl_xor(p0, 1); p0 += __shfl_xor(p0, 2);
                p0 += __shfl_xor(p0, 4); p0 += __shfl_xor(p0, 8);
                p1 += __shfl_xor(p1, 1); p1 += __shfl_xor(p1, 2);
                p1 += __shfl_xor(p1, 4); p1 += __shfl_xor(p1, 8);
                if (l15 == 0) {
                    int row = mt5 * 16 + quad * 4 + i;
                    part[((wv >> 1) * BM + row) * 2]     = p0;
                    part[((wv >> 1) * BM + row) * 2 + 1] = p1;
                }
            }
            __syncthreads();   // bar8
            if (tid < BM) {
                int r = tid;
                float s0 = by0, s1 = by1;
#pragma unroll
                for (int j = 0; j < 8; ++j) {
                    s0 += part[(j * BM + r) * 2];
                    s1 += part[(j * BM + r) * 2 + 1];
                }
                float mx = fmaxf(s0, s1);
                float e0 = __expf(s0 - mx), e1 = __expf(s1 - mx);
                float inv = 1.f / (e0 + e1);
                size_t yoff = ((size_t)(b0 + r) * T_SZ + t) * YD;
                out[yoff]     = e0 * inv;
                out[yoff + 1] = e1 * inv;
            }
        }
    }
}

extern "C" void kernel_launch(void* const* d_in, const int* in_sizes, int n_in,
                              void* d_out, int out_size, void* d_ws, size_t ws_size,
                              hipStream_t stream)
{
    const float* x   = (const float*)d_in[0];
    const float* yph = (const float*)d_in[1];
    const int*   Tph = (const int*)  d_in[2];
    const float* h0  = (const float*)d_in[3];
    const float* z0  = (const float*)d_in[4];
    const float* eps = (const float*)d_in[5];
    const float* Wr  = (const float*)d_in[6];
    const float* br  = (const float*)d_in[7];
    const float* Wu  = (const float*)d_in[8];
    const float* bu  = (const float*)d_in[9];
    const float* Wh  = (const float*)d_in[10];
    const float* bh  = (const float*)d_in[11];
    const float* Wzp = (const float*)d_in[12];
    const float* bzp = (const float*)d_in[13];
    const float* Wpm = (const float*)d_in[14];
    const float* bpm = (const float*)d_in[15];
    const float* Wps = (const float*)d_in[16];
    const float* bps = (const float*)d_in[17];
    const float* Wzq = (const float*)d_in[18];
    const float* bzq = (const float*)d_in[19];
    const float* Wqm = (const float*)d_in[20];
    const float* bqm = (const float*)d_in[21];
    const float* Wqs = (const float*)d_in[22];
    const float* bqs = (const float*)d_in[23];
    const float* Wg  = (const float*)d_in[24];
    const float* bg  = (const float*)d_in[25];
    const float* Wy  = (const float*)d_in[26];
    const float* by  = (const float*)d_in[27];
    u16*   wts = (u16*)d_ws;
    float* out = (float*)d_out;

    hipLaunchKernelGGL(prep_weights, dim3((WTOT + 255) / 256), dim3(256), 0, stream,
                       Wr, Wu, Wh, Wzp, Wzq, Wpm, Wps, Wqm, Wqs, Wg, wts);
    hipLaunchKernelGGL(vrnn_all, dim3(B_SZ / BM), dim3(1024), 0, stream,
                       x, yph, Tph, h0, z0, eps, br, bu, bh, bzp, bpm, bps,
                       bzq, bqm, bqs, bg, by, Wy, wts, out);
}